// Round 13
// baseline (327.100 us; speedup 1.0000x reference)
//
#include <hip/hip_runtime.h>
#include <hip/hip_cooperative_groups.h>

namespace cg = cooperative_groups;

// ---------------------------------------------------------------------------
// GCN_35107062677929: 3-layer GCN, N=50000, E=800000, D=128.
//
// Round 13: cooperative mega-kernel, hardened after r12's silent launch
// failure (hipLaunchCooperativeKernel rejected the hardcoded 512-block grid;
// output stayed zero, test returned in 2s => immediate error, not deadlock):
//  (a) gemm2x LDS 51.2->33.8 KB (xs aliases ys; xs dead after stage-1 MFMA,
//      extra __syncthreads guards the overlap).
//  (b) grid = hipOccupancyMaxActiveBlocksPerMultiprocessor x numCU (rounded
//      to x8 for the XCD-partitioned scatter), phases stride by gridDim.x.
//  (c) launch return code CHECKED; on any failure fall back to the proven
//      r11 8-dispatch path (same phase bodies wrapped as plain kernels).
// Phases: P0 zero cnt + weight transpose | P1 XCD-partitioned scatter |
// P2 gemm1 | P3 agg | P4 gemm2x | P5 agg | P6 gemm3 | P7 final agg+dot.
// ---------------------------------------------------------------------------

#define LRELU(v) ((v) > 0.f ? (v) : 0.01f * (v))

typedef __attribute__((ext_vector_type(8))) _Float16 half8;
typedef __attribute__((ext_vector_type(8))) float float8;
typedef __attribute__((ext_vector_type(4))) float floatx4;

constexpr int CAP = 64;       // padded edge-list capacity (max deg ~40)
constexpr int SMEM_H = 16896; // 64*264 halves = 33.8 KB (gemm2x ys tile)

// ---------------------------------------------------------------------------
// GEMM phase body. tile loop strides by gridDim.x.
// EPI 0: dis*lrelu(acc+b)  EPI 2: dis*acc   (dis = rsqrt(cnt+1))
// ---------------------------------------------------------------------------
template <int K, int F, int EPI, typename IT>
__device__ void phase_gemm(const IT* __restrict__ X,
                           const _Float16* __restrict__ Wt,
                           const float* __restrict__ b,
                           const int* __restrict__ cnt,
                           _Float16* __restrict__ out, int M,
                           _Float16* xs) {
  constexpr int TM = 64;
  constexpr int LK = K + 8;
  constexpr int CW = F / 4;
  constexpr int NT = CW / 16;
  constexpr int NK = K / 32;

  const int tid = threadIdx.x;
  const int w = tid >> 6;
  const int lane = tid & 63;
  const int m = lane & 15;
  const int q = lane >> 4;
  const int nTiles = (M + TM - 1) / TM;

  half8 breg[NT][NK];
#pragma unroll
  for (int t = 0; t < NT; ++t)
#pragma unroll
    for (int kc = 0; kc < NK; ++kc)
      breg[t][kc] =
          *(const half8*)&Wt[(long)(w * CW + t * 16 + m) * K + kc * 32 + q * 8];

  for (int tile = blockIdx.x; tile < nTiles; tile += gridDim.x) {
    const int m0 = tile * TM;
    __syncthreads();  // xs reuse guard
    constexpr int CPR = K / 8;
    for (int idx = tid; idx < TM * CPR; idx += 256) {
      const int row = idx / CPR;
      const int kk = idx % CPR;
      const int g = m0 + row;
      half8 h = (half8)(_Float16)0.f;
      if (g < M) {
        if constexpr (sizeof(IT) == 4) {
          const float4* p = (const float4*)&X[(long)g * K + kk * 8];
          float4 a = p[0], c = p[1];
          h[0] = (_Float16)a.x; h[1] = (_Float16)a.y;
          h[2] = (_Float16)a.z; h[3] = (_Float16)a.w;
          h[4] = (_Float16)c.x; h[5] = (_Float16)c.y;
          h[6] = (_Float16)c.z; h[7] = (_Float16)c.w;
        } else {
          h = *(const half8*)&X[(long)g * K + kk * 8];
        }
      }
      *(half8*)&xs[row * LK + kk * 8] = h;
    }
    __syncthreads();

    floatx4 acc[4][NT];
#pragma unroll
    for (int rt = 0; rt < 4; ++rt)
#pragma unroll
      for (int t = 0; t < NT; ++t) acc[rt][t] = (floatx4){0.f, 0.f, 0.f, 0.f};

#pragma unroll
    for (int kc = 0; kc < NK; ++kc) {
      half8 af[4];
#pragma unroll
      for (int rt = 0; rt < 4; ++rt)
        af[rt] = *(const half8*)&xs[(rt * 16 + m) * LK + kc * 32 + q * 8];
#pragma unroll
      for (int rt = 0; rt < 4; ++rt)
#pragma unroll
        for (int t = 0; t < NT; ++t)
          acc[rt][t] = __builtin_amdgcn_mfma_f32_16x16x32_f16(
              af[rt], breg[t][kc], acc[rt][t], 0, 0, 0);
    }

#pragma unroll
    for (int rt = 0; rt < 4; ++rt) {
#pragma unroll
      for (int r = 0; r < 4; ++r) {
        const int row = m0 + rt * 16 + q * 4 + r;
        if (row < M) {
          const float dv = rsqrtf((float)cnt[row] + 1.0f);
#pragma unroll
          for (int t = 0; t < NT; ++t) {
            const int col = w * CW + t * 16 + m;
            float v = acc[rt][t][r];
            if constexpr (EPI == 0) { v += b[col]; v = LRELU(v); v *= dv; }
            if constexpr (EPI == 2) { v *= dv; }
            out[(long)row * F + col] = (_Float16)v;
          }
        }
      }
    }
  }
}

// ---------------------------------------------------------------------------
// Fused gemm2+gemm3: a0 -> h1 = lrelu(a0@W1+b1) (LDS) -> dis*(h1@W2).
// xs (64x136) ALIASES ys (64x264): xs is dead after stage-1 MFMAs.
// ---------------------------------------------------------------------------
__device__ void phase_gemm2x(const _Float16* __restrict__ X,
                             const _Float16* __restrict__ Wt1,
                             const float* __restrict__ b1,
                             const _Float16* __restrict__ Wt2,
                             const int* __restrict__ cnt,
                             _Float16* __restrict__ out, int M,
                             _Float16* smem) {
  constexpr int TM = 64;
  constexpr int LK1 = 128 + 8;
  constexpr int LK2 = 256 + 8;
  _Float16* xs = smem;   // 8704 halves, aliased by ys
  _Float16* ys = smem;   // 16896 halves

  const int tid = threadIdx.x;
  const int w = tid >> 6;
  const int lane = tid & 63;
  const int m = lane & 15;
  const int q = lane >> 4;
  const int nTiles = (M + TM - 1) / TM;

  half8 breg1[4][4];
#pragma unroll
  for (int t = 0; t < 4; ++t)
#pragma unroll
    for (int kc = 0; kc < 4; ++kc)
      breg1[t][kc] = *(const half8*)&Wt1[(long)(w * 64 + t * 16 + m) * 128 +
                                         kc * 32 + q * 8];
  half8 breg2[2][8];
#pragma unroll
  for (int t = 0; t < 2; ++t)
#pragma unroll
    for (int kc = 0; kc < 8; ++kc)
      breg2[t][kc] = *(const half8*)&Wt2[(long)(w * 32 + t * 16 + m) * 256 +
                                         kc * 32 + q * 8];

  for (int tile = blockIdx.x; tile < nTiles; tile += gridDim.x) {
    const int m0 = tile * TM;
    __syncthreads();  // smem reuse guard (prev iter stage-2 reads)
    for (int idx = tid; idx < TM * 16; idx += 256) {
      const int row = idx >> 4;
      const int kk = idx & 15;
      const int g = m0 + row;
      half8 h = (half8)(_Float16)0.f;
      if (g < M) h = *(const half8*)&X[(long)g * 128 + kk * 8];
      *(half8*)&xs[row * LK1 + kk * 8] = h;
    }
    __syncthreads();

    floatx4 acc1[4][4];
#pragma unroll
    for (int rt = 0; rt < 4; ++rt)
#pragma unroll
      for (int t = 0; t < 4; ++t) acc1[rt][t] = (floatx4){0.f, 0.f, 0.f, 0.f};

#pragma unroll
    for (int kc = 0; kc < 4; ++kc) {
      half8 af[4];
#pragma unroll
      for (int rt = 0; rt < 4; ++rt)
        af[rt] = *(const half8*)&xs[(rt * 16 + m) * LK1 + kc * 32 + q * 8];
#pragma unroll
      for (int rt = 0; rt < 4; ++rt)
#pragma unroll
        for (int t = 0; t < 4; ++t)
          acc1[rt][t] = __builtin_amdgcn_mfma_f32_16x16x32_f16(
              af[rt], breg1[t][kc], acc1[rt][t], 0, 0, 0);
    }
    __syncthreads();  // all waves done reading xs before ys overwrites it

#pragma unroll
    for (int rt = 0; rt < 4; ++rt) {
#pragma unroll
      for (int r = 0; r < 4; ++r) {
        const int row = rt * 16 + q * 4 + r;
#pragma unroll
        for (int t = 0; t < 4; ++t) {
          const int col = w * 64 + t * 16 + m;
          float v = acc1[rt][t][r] + b1[col];
          ys[row * LK2 + col] = (_Float16)LRELU(v);
        }
      }
    }
    __syncthreads();

    floatx4 acc2[4][2];
#pragma unroll
    for (int rt = 0; rt < 4; ++rt)
#pragma unroll
      for (int t = 0; t < 2; ++t) acc2[rt][t] = (floatx4){0.f, 0.f, 0.f, 0.f};

#pragma unroll
    for (int kc = 0; kc < 8; ++kc) {
      half8 af[4];
#pragma unroll
      for (int rt = 0; rt < 4; ++rt)
        af[rt] = *(const half8*)&ys[(rt * 16 + m) * LK2 + kc * 32 + q * 8];
#pragma unroll
      for (int rt = 0; rt < 4; ++rt)
#pragma unroll
        for (int t = 0; t < 2; ++t)
          acc2[rt][t] = __builtin_amdgcn_mfma_f32_16x16x32_f16(
              af[rt], breg2[t][kc], acc2[rt][t], 0, 0, 0);
    }

#pragma unroll
    for (int rt = 0; rt < 4; ++rt) {
#pragma unroll
      for (int r = 0; r < 4; ++r) {
        const int row = m0 + rt * 16 + q * 4 + r;
        if (row < M) {
          const float dv = rsqrtf((float)cnt[row] + 1.0f);
#pragma unroll
          for (int t = 0; t < 2; ++t) {
            const int col = w * 32 + t * 16 + m;
            out[(long)row * 128 + col] = (_Float16)(acc2[rt][t][r] * dv);
          }
        }
      }
    }
  }
}

// ---------------------------------------------------------------------------
// Aggregation phase (paired/phased). Wave = 2 nodes; lane = n*32 + jj*8 + c.
// F=128: 2 column phases (64 cols = 1 TCC line).
// MODE 0: dis*acc   MODE 1: lrelu(dis*acc+b)   MODE 2: fused final dot.
// ---------------------------------------------------------------------------
template <int F, int MODE>
__device__ void phase_agg(const _Float16* __restrict__ G,
                          const unsigned short* __restrict__ pad,
                          const int* __restrict__ cnt,
                          const float* __restrict__ b,
                          const float* __restrict__ Wout,
                          const float* __restrict__ bout,
                          void* __restrict__ out, int N) {
  const int w = threadIdx.x >> 6;
  const int lane = threadIdx.x & 63;
  const int c = lane & 7;
  const int j = lane >> 3;
  const int n = j >> 2;
  const int jj = j & 3;
  const int uBlk = (N + 7) / 8;
  const int nUnits = (F == 128) ? 2 * uBlk : uBlk;

  for (int u = blockIdx.x; u < nUnits; u += gridDim.x) {
    const int y = (F == 128) ? (u / uBlk) : 0;
    const int ub = (F == 128) ? (u % uBlk) : u;
    int i = ub * 8 + w * 2 + n;
    const bool valid = (i < N);
    if (!valid) i = N - 1;
    const int col0 = y << 6;

    const _Float16* gbase = G + col0 + c * 8;
    const int cn = min(cnt[i], CAP);
    const unsigned short* plist = pad + (long)i * CAP;

    float8 acc = {0.f, 0.f, 0.f, 0.f, 0.f, 0.f, 0.f, 0.f};
    if (jj == 0)  // self term
      acc = __builtin_convertvector(*(const half8*)(gbase + (long)i * F), float8);
    for (int e = jj; e < cn; e += 4) {
      const int s = plist[e];
      acc += __builtin_convertvector(*(const half8*)(gbase + (long)s * F), float8);
    }
#pragma unroll
    for (int k = 0; k < 8; ++k) {
      acc[k] += __shfl_xor(acc[k], 8);
      acc[k] += __shfl_xor(acc[k], 16);
    }

    const float dv = rsqrtf((float)cnt[i] + 1.0f);
    if constexpr (MODE == 2) {
      float p = 0.f;
#pragma unroll
      for (int k = 0; k < 8; ++k) {
        const int col = c * 8 + k;
        float v = acc[k] * dv + b[col];
        v = LRELU(v);
        p += v * Wout[col];
      }
      p += __shfl_xor(p, 1);
      p += __shfl_xor(p, 2);
      p += __shfl_xor(p, 4);
      if (valid && jj == 0 && c == 0) ((float*)out)[i] = p + bout[0];
    } else {
      if (valid && jj == 0) {
        half8 hv;
#pragma unroll
        for (int k = 0; k < 8; ++k) {
          float v = acc[k] * dv;
          if constexpr (MODE == 1) { v += b[col0 + c * 8 + k]; v = LRELU(v); }
          hv[k] = (_Float16)v;
        }
        *(half8*)&((_Float16*)out)[(long)i * F + col0 + c * 8] = hv;
      }
    }
  }
}

// ---------------------------------------------------------------------------
// Mega-kernel (cooperative).
// ---------------------------------------------------------------------------
__global__ __launch_bounds__(256, 2) void k_mega(
    const float* __restrict__ x, const int* __restrict__ src,
    const int* __restrict__ dst, const float* __restrict__ W_in,
    const float* __restrict__ b_in, const float* __restrict__ W1,
    const float* __restrict__ b1, const float* __restrict__ W2,
    const float* __restrict__ b2, const float* __restrict__ W3,
    const float* __restrict__ b3, const float* __restrict__ W_out,
    const float* __restrict__ b_out, int* __restrict__ cnt,
    unsigned short* __restrict__ pad, _Float16* __restrict__ wt_in,
    _Float16* __restrict__ wt1, _Float16* __restrict__ wt2,
    _Float16* __restrict__ wt3, _Float16* __restrict__ buf1,
    _Float16* __restrict__ buf2, _Float16* __restrict__ buf3,
    float* __restrict__ out, int N, int E, int PR) {
  cg::grid_group grid = cg::this_grid();
  __shared__ _Float16 smem[SMEM_H];  // 33.8 KB

  const int tid = threadIdx.x;
  const int b = blockIdx.x;
  const int gid = b * 256 + tid;
  const int GS = gridDim.x * 256;

  // ---- P0: zero cnt + weight transpose/convert ----
  for (int i = gid; i < N; i += GS) cnt[i] = 0;
  for (int i = gid; i < 128 * 128; i += GS) {
    const int k = i >> 7, f = i & 127;
    wt_in[f * 128 + k] = (_Float16)W_in[i];
  }
  for (int i = gid; i < 128 * 256; i += GS) {
    const int k = i >> 8, f = i & 255;
    wt1[f * 128 + k] = (_Float16)W1[i];
  }
  for (int i = gid; i < 256 * 128; i += GS) {
    const int k = i >> 7, f = i & 127;
    wt2[f * 256 + k] = (_Float16)W2[i];
  }
  for (int i = gid; i < 128 * 64; i += GS) {
    const int k = i >> 6, f = i & 63;
    wt3[f * 128 + k] = (_Float16)W3[i];
  }
  grid.sync();

  // ---- P1: XCD-partitioned padded-CSR scatter (gridDim.x % 8 == 0) ----
  {
    const int range = b & 7;
    const int stride = (gridDim.x >> 3) * 256;
    for (int e = (b >> 3) * 256 + tid; e < E; e += stride) {
      const int d = dst[e];
      if (d / PR == range) {
        const int pos = atomicAdd(&cnt[d], 1);
        if (pos < CAP) pad[(long)d * CAP + pos] = (unsigned short)src[e];
      }
    }
  }
  grid.sync();

  // ---- P2: g0 = dis .* lrelu(x @ W_in + b_in) ----
  phase_gemm<128, 128, 0, float>(x, wt_in, b_in, cnt, buf1, N, smem);
  grid.sync();
  // ---- P3: a0 = A g0 ----
  phase_agg<128, 0>(buf1, pad, cnt, nullptr, nullptr, nullptr, buf2, N);
  grid.sync();
  // ---- P4: g2 = dis .* (lrelu(a0 @ W1 + b1) @ W2) ----
  phase_gemm2x(buf2, wt1, b1, wt2, cnt, buf1, N, smem);
  grid.sync();
  // ---- P5: h2 = lrelu(A g2 + b2) ----
  phase_agg<128, 1>(buf1, pad, cnt, b2, nullptr, nullptr, buf2, N);
  grid.sync();
  // ---- P6: g3 = dis .* (h2 @ W3) ----
  phase_gemm<128, 64, 2, _Float16>(buf2, wt3, nullptr, cnt, buf3, N, smem);
  grid.sync();
  // ---- P7: out = lrelu(A g3 + b3) @ W_out + b_out ----
  phase_agg<64, 2>(buf3, pad, cnt, b3, W_out, b_out, out, N);
}

// ---------------------------------------------------------------------------
// Fallback kernels (r11 path), reusing the phase bodies.
// ---------------------------------------------------------------------------
__global__ __launch_bounds__(256) void k_prep(const int* __restrict__ src,
                                              const int* __restrict__ dst,
                                              int* __restrict__ cnt,
                                              unsigned short* __restrict__ pad,
                                              const float* __restrict__ W_in,
                                              const float* __restrict__ W1,
                                              const float* __restrict__ W2,
                                              const float* __restrict__ W3,
                                              _Float16* __restrict__ wt_in,
                                              _Float16* __restrict__ wt1,
                                              _Float16* __restrict__ wt2,
                                              _Float16* __restrict__ wt3,
                                              int E, int PR) {
  const int b = blockIdx.x;
  const int tid = threadIdx.x;
  if (b < 128) {
    const int m = b >> 5;
    const int idx = (b & 31) * 256 + tid;
    if (m == 0) {
      for (int i = idx; i < 128 * 128; i += 8192) {
        const int k = i >> 7, f = i & 127;
        wt_in[f * 128 + k] = (_Float16)W_in[i];
      }
    } else if (m == 1) {
      for (int i = idx; i < 128 * 256; i += 8192) {
        const int k = i >> 8, f = i & 255;
        wt1[f * 128 + k] = (_Float16)W1[i];
      }
    } else if (m == 2) {
      for (int i = idx; i < 256 * 128; i += 8192) {
        const int k = i >> 7, f = i & 127;
        wt2[f * 256 + k] = (_Float16)W2[i];
      }
    } else {
      for (int i = idx; i < 128 * 64; i += 8192) {
        const int k = i >> 6, f = i & 63;
        wt3[f * 128 + k] = (_Float16)W3[i];
      }
    }
  } else {
    const int bb = b - 128;
    const int range = bb & 7;
    const int e = (bb >> 3) * 256 + tid;
    if (e < E) {
      const int d = dst[e];
      if (d / PR == range) {
        const int pos = atomicAdd(&cnt[d], 1);
        if (pos < CAP) pad[(long)d * CAP + pos] = (unsigned short)src[e];
      }
    }
  }
}

template <int K, int F, int EPI, typename IT>
__global__ __launch_bounds__(256) void k_gemm(const IT* __restrict__ X,
                                              const _Float16* __restrict__ Wt,
                                              const float* __restrict__ b,
                                              const int* __restrict__ cnt,
                                              _Float16* __restrict__ out, int M) {
  __shared__ _Float16 smem[64 * (K + 8)];
  phase_gemm<K, F, EPI, IT>(X, Wt, b, cnt, out, M, smem);
}

__global__ __launch_bounds__(256) void k_gemm2x(const _Float16* __restrict__ X,
                                                const _Float16* __restrict__ Wt1,
                                                const float* __restrict__ b1,
                                                const _Float16* __restrict__ Wt2,
                                                const int* __restrict__ cnt,
                                                _Float16* __restrict__ out,
                                                int M) {
  __shared__ _Float16 smem[SMEM_H];
  phase_gemm2x(X, Wt1, b1, Wt2, cnt, out, M, smem);
}

template <int F, int MODE>
__global__ __launch_bounds__(256) void k_agg(const _Float16* __restrict__ G,
                                             const unsigned short* __restrict__ pad,
                                             const int* __restrict__ cnt,
                                             const float* __restrict__ b,
                                             const float* __restrict__ Wout,
                                             const float* __restrict__ bout,
                                             void* __restrict__ out, int N) {
  phase_agg<F, MODE>(G, pad, cnt, b, Wout, bout, out, N);
}

// ---------------------------------------------------------------------------

extern "C" void kernel_launch(void* const* d_in, const int* in_sizes, int n_in,
                              void* d_out, int out_size, void* d_ws, size_t ws_size,
                              hipStream_t stream) {
  const float* x     = (const float*)d_in[0];
  const int* eidx    = (const int*)d_in[1];
  const float* W_in  = (const float*)d_in[2];
  const float* b_in  = (const float*)d_in[3];
  const float* W1    = (const float*)d_in[4];
  const float* b1    = (const float*)d_in[5];
  const float* W2    = (const float*)d_in[6];
  const float* b2    = (const float*)d_in[7];
  const float* W3    = (const float*)d_in[8];
  const float* b3    = (const float*)d_in[9];
  const float* W_out = (const float*)d_in[10];
  const float* b_out = (const float*)d_in[11];
  float* out = (float*)d_out;

  int N = in_sizes[0] / 128;  // 50000 (< 65536: ushort pad entries)
  int E = in_sizes[1] / 2;
  const int* src = eidx;
  const int* dst = eidx + E;
  int PR = (N + 7) / 8;

  // bump allocator on d_ws, 256 B aligned
  size_t off = 0;
  char* base = (char*)d_ws;
  auto alloc = [&](size_t bytes) -> void* {
    void* p = base + off;
    off = (off + bytes + 255) & ~(size_t)255;
    return p;
  };
  int* cnt            = (int*)alloc((size_t)N * sizeof(int));
  unsigned short* pad = (unsigned short*)alloc((size_t)N * CAP * 2);
  _Float16* wt_in     = (_Float16*)alloc((size_t)128 * 128 * 2);
  _Float16* wt1       = (_Float16*)alloc((size_t)256 * 128 * 2);
  _Float16* wt2       = (_Float16*)alloc((size_t)128 * 256 * 2);
  _Float16* wt3       = (_Float16*)alloc((size_t)64 * 128 * 2);
  _Float16* buf1      = (_Float16*)alloc((size_t)N * 128 * 2);
  _Float16* buf2      = (_Float16*)alloc((size_t)N * 128 * 2);
  _Float16* buf3      = (_Float16*)alloc((size_t)N * 64 * 2);

  // ---- cooperative grid sizing (query, don't assume) ----
  int dev = 0;
  hipGetDevice(&dev);
  int numCU = 0;
  hipDeviceGetAttribute(&numCU, hipDeviceAttributeMultiprocessorCount, dev);
  int maxB = 0;
  hipError_t qe = hipOccupancyMaxActiveBlocksPerMultiprocessor(
      &maxB, (const void*)k_mega, 256, 0);
  int grid = (qe == hipSuccess && numCU > 0) ? maxB * numCU : 0;
  grid &= ~7;                      // P1 needs gridDim.x % 8 == 0
  if (grid > 2048) grid = 2048;

  bool coop = (grid >= 8);
  if (coop) {
    void* kargs[] = {
        (void*)&x,     (void*)&src,  (void*)&dst,  (void*)&W_in,
        (void*)&b_in,  (void*)&W1,   (void*)&b1,   (void*)&W2,
        (void*)&b2,    (void*)&W3,   (void*)&b3,   (void*)&W_out,
        (void*)&b_out, (void*)&cnt,  (void*)&pad,  (void*)&wt_in,
        (void*)&wt1,   (void*)&wt2,  (void*)&wt3,  (void*)&buf1,
        (void*)&buf2,  (void*)&buf3, (void*)&out,  (void*)&N,
        (void*)&E,     (void*)&PR};
    hipError_t le = hipLaunchCooperativeKernel((const void*)k_mega, dim3(grid),
                                               dim3(256), kargs, 0, stream);
    coop = (le == hipSuccess);
  }

  if (!coop) {
    // ---- fallback: proven r11 8-dispatch path ----
    const int gE = (E + 255) / 256;
    const int gRows = (N + 63) / 64;
    const int gAggP = (N + 7) / 8;
    hipMemsetAsync(cnt, 0, (size_t)N * sizeof(int), stream);
    k_prep<<<128 + 8 * gE, 256, 0, stream>>>(src, dst, cnt, pad, W_in, W1, W2,
                                             W3, wt_in, wt1, wt2, wt3, E, PR);
    k_gemm<128, 128, 0, float><<<gRows, 256, 0, stream>>>(x, wt_in, b_in, cnt,
                                                          buf1, N);
    k_agg<128, 0><<<2 * gAggP, 256, 0, stream>>>(buf1, pad, cnt, nullptr,
                                                 nullptr, nullptr, buf2, N);
    k_gemm2x<<<gRows, 256, 0, stream>>>(buf2, wt1, b1, wt2, cnt, buf1, N);
    k_agg<128, 1><<<2 * gAggP, 256, 0, stream>>>(buf1, pad, cnt, b2, nullptr,
                                                 nullptr, buf2, N);
    k_gemm<128, 64, 2, _Float16><<<gRows, 256, 0, stream>>>(buf2, wt3, nullptr,
                                                            cnt, buf3, N);
    k_agg<64, 2><<<gAggP, 256, 0, stream>>>(buf3, pad, cnt, b3, W_out, b_out,
                                            out, N);
  }
}